// Round 5
// baseline (478.589 us; speedup 1.0000x reference)
//
#include <hip/hip_runtime.h>
#include <math.h>

#define BB 512
#define TT 512
#define OO 64

// =====================================================================
// Kernel 1: transpose trans (16 KB) into ws so conf-pass rows coalesce
// Tt[g*64+i] = trans[i*64+g] = T[i][g]
// =====================================================================
__global__ void crf_transpose(const float* __restrict__ trans,
                              float* __restrict__ Tt) {
    for (int k = threadIdx.x; k < OO * OO; k += 256)
        Tt[k] = trans[(k & 63) * OO + (k >> 6)];
}

// =====================================================================
// Kernel 2: single-wave Viterbi scan, NO in-loop argmax.
// Lane j owns tag j. Broadcast via grouped readlanes; candidates are
// consumed immediately into a micro max-tree (low register pressure).
// Streams M_t (pre-emission max) to ws; backpointers recovered exactly
// in a fused ballot-backtrack (fmax is exact selection => d == M match).
// =====================================================================
__global__ __launch_bounds__(64) void crf_scan(
    const float* __restrict__ logits,   // [B][T][O]
    const float* __restrict__ trans,    // [O][O]
    const int*   __restrict__ seqlens,  // [B]
    float* __restrict__ out_tags,       // [B][T] (f32)
    float* __restrict__ Mst)            // ws: [B][T][O] f32  (M_0 = 0 row)
{
    const int b = blockIdx.x;
    const int j = threadIdx.x;          // tag 0..63 (also "i" in backtrack)

    __shared__ float Tt_lds[OO * OO];   // Tt_lds[g*64+i] = T[i][g]
    __shared__ unsigned char tagl[TT];

    const int L = seqlens[b];
    const float* lg = logits + (size_t)b * TT * OO;
    float* Mw = Mst + (size_t)b * TT * OO;

    // lane j: load column T[:][j] into regs (coalesced) and mirror into
    // the transposed LDS copy (one-time 64-way bank conflict, off-loop).
    float Tc[64];
    #pragma unroll
    for (int r = 0; r < 64; ++r) {
        float v = trans[r * OO + j];
        Tc[r] = v;
        Tt_lds[j * OO + r] = v;
    }

    float s = lg[j];                    // state in register, one per lane
    Mw[j] = 0.f;                        // M_0 := 0  (s_0 = x_0 + M_0)

    float xr1 = (L > 1) ? lg[OO + j] : 0.f;       // 2-deep emission prefetch
    float xr2 = (L > 2) ? lg[2 * OO + j] : 0.f;

    for (int t = 1; t < L; ++t) {
        float x = xr1;
        xr1 = xr2;
        if (t + 2 < L) xr2 = lg[(t + 2) * OO + j];

        // grouped broadcast + micro-tree: candidates die immediately
        float m;
        #pragma unroll
        for (int g = 0; g < 8; ++g) {
            unsigned su = __float_as_uint(s);
            float c0 = __uint_as_float((unsigned)__builtin_amdgcn_readlane(su, 8*g+0)) + Tc[8*g+0];
            float c1 = __uint_as_float((unsigned)__builtin_amdgcn_readlane(su, 8*g+1)) + Tc[8*g+1];
            float c2 = __uint_as_float((unsigned)__builtin_amdgcn_readlane(su, 8*g+2)) + Tc[8*g+2];
            float c3 = __uint_as_float((unsigned)__builtin_amdgcn_readlane(su, 8*g+3)) + Tc[8*g+3];
            float c4 = __uint_as_float((unsigned)__builtin_amdgcn_readlane(su, 8*g+4)) + Tc[8*g+4];
            float c5 = __uint_as_float((unsigned)__builtin_amdgcn_readlane(su, 8*g+5)) + Tc[8*g+5];
            float c6 = __uint_as_float((unsigned)__builtin_amdgcn_readlane(su, 8*g+6)) + Tc[8*g+6];
            float c7 = __uint_as_float((unsigned)__builtin_amdgcn_readlane(su, 8*g+7)) + Tc[8*g+7];
            float t01 = fmaxf(c0, c1), t23 = fmaxf(c2, c3);
            float t45 = fmaxf(c4, c5), t67 = fmaxf(c6, c7);
            float mg = fmaxf(fmaxf(t01, t23), fmaxf(t45, t67));
            m = (g == 0) ? mg : fmaxf(m, mg);
        }

        Mw[t * OO + j] = m;             // stream the pre-emission max
        s = x + m;                      // loop-carried: pure registers
    }

    // ---- final argmax over lanes (first-max, exact) ----
    float mm = s;
    #pragma unroll
    for (int d = 1; d < 64; d <<= 1)
        mm = fmaxf(mm, __shfl_xor(mm, d));
    unsigned long long bal = __ballot(s == mm);
    int gcur = (int)__builtin_ctzll(bal);

    // ---- fused exact backtrack: find first i with d_i == M_t[gcur] ----
    int t = L - 1;
    if (j == 0) tagl[t] = (unsigned char)gcur;

    float Mt = Mw[t * OO + j];                          // M_t row (per-lane)
    float Xp = (t >= 1) ? lg[(t - 1) * OO + j] : 0.f;   // x_{t-1} row
    float Mp = (t >= 1) ? Mw[(t - 1) * OO + j] : 0.f;   // M_{t-1} row
    float Xq = (t >= 2) ? lg[(t - 2) * OO + j] : 0.f;   // prefetch t-2
    float Mq = (t >= 2) ? Mw[(t - 2) * OO + j] : 0.f;

    while (t >= 1) {
        float target = __uint_as_float(
            (unsigned)__builtin_amdgcn_readlane(__float_as_uint(Mt), gcur));
        float d = (Xp + Mp) + Tt_lds[gcur * OO + j];    // bit-exact recompute
        unsigned long long bl = __ballot(d == target);
        gcur = (int)__builtin_ctzll(bl);                // first-max semantics
        if (j == 0) tagl[t - 1] = (unsigned char)gcur;
        Mt = Mp; Xp = Xq; Mp = Mq;
        if (t >= 3) {
            Xq = lg[(t - 3) * OO + j];
            Mq = Mw[(t - 3) * OO + j];
        }
        --t;
    }
    asm volatile("" ::: "memory");      // lane0 tagl writes before wave reads

    float* ot = out_tags + (size_t)b * TT;
    for (int p = j; p < TT; p += 64)
        ot[p] = (p < L) ? (float)tagl[p] : 0.f;
}

// =====================================================================
// Kernel 3: confidences for decoded path only. One wave per (b,p).
// s_p = x_p + M_p (bit-exact reconstruction);
// conf = 1 / sum_i exp(v_i - max v),  v_i = s_p[i] + T[i][tag_{p+1}]
// (v_i = s_p[i] for p == L-1). Exact f32.
// =====================================================================
__global__ __launch_bounds__(256) void crf_conf(
    const float* __restrict__ logits,   // [B][T][O]
    const float* __restrict__ Mst,      // ws: [B][T][O]
    const float* __restrict__ Tt,       // ws: [O][O] transposed
    const float* __restrict__ out_tags, // [B][T]
    const int*   __restrict__ seqlens,  // [B]
    float* __restrict__ out_scores)     // [B][T]
{
    const int b = blockIdx.x >> 7;
    const int p = ((blockIdx.x & 127) << 2) + (threadIdx.x >> 6);
    const int i = threadIdx.x & 63;
    const int L = seqlens[b];

    if (p >= L) {
        if (i == 0) out_scores[(size_t)b * TT + p] = 0.f;
        return;
    }

    const size_t row = ((size_t)b * TT + p) * OO;
    float v = logits[row + i] + Mst[row + i];
    if (p < L - 1) {
        int g = (int)out_tags[(size_t)b * TT + p + 1];
        v += Tt[g * OO + i];
    }

    float m = v;
    #pragma unroll
    for (int d = 1; d < 64; d <<= 1)
        m = fmaxf(m, __shfl_xor(m, d));
    float e = __expf(v - m);
    #pragma unroll
    for (int d = 1; d < 64; d <<= 1)
        e += __shfl_xor(e, d);

    if (i == 0)
        out_scores[(size_t)b * TT + p] = 1.0f / e;
}

// =====================================================================
// Fallback (proven round-1 kernel): used only if ws too small
// =====================================================================
__global__ __launch_bounds__(256) void crf_decode_fallback(
    const float* __restrict__ logits,
    const float* __restrict__ trans,
    const int*   __restrict__ seqlens,
    float* __restrict__ out)
{
    const int b   = blockIdx.x;
    const int tid = threadIdx.x;
    const int j   = tid >> 2;
    const int c   = tid & 3;

    __shared__ unsigned char bpl[TT][OO];
    __shared__ unsigned char scl[TT][OO];
    __shared__ float st[2][OO];

    const int L = seqlens[b];
    const float* lg = logits + (size_t)b * TT * OO;

    float trc[16];
    #pragma unroll
    for (int i2 = 0; i2 < 16; ++i2)
        trc[i2] = trans[(c * 16 + i2) * OO + j];

    if (tid < OO) st[0][tid] = lg[tid];
    __syncthreads();

    int cur = 0;
    for (int t = 1; t < L; ++t) {
        float x = lg[t * OO + j];
        float v[16];
        float m = -1e30f;
        int   idx = 0;
        #pragma unroll
        for (int i2 = 0; i2 < 16; ++i2) {
            float val = st[cur][c * 16 + i2] + trc[i2];
            v[i2] = val;
            if (val > m) { m = val; idx = c * 16 + i2; }
        }
        #pragma unroll
        for (int d = 1; d <= 2; d <<= 1) {
            float mo = __shfl_xor(m, d);
            int   io = __shfl_xor(idx, d);
            if (mo > m || (mo == m && io < idx)) { m = mo; idx = io; }
        }
        float sden = 0.f;
        #pragma unroll
        for (int i2 = 0; i2 < 16; ++i2)
            sden += __expf(v[i2] - m);
        #pragma unroll
        for (int d = 1; d <= 2; d <<= 1)
            sden += __shfl_xor(sden, d);

        if (c == 0) {
            st[cur ^ 1][j] = x + m;
            bpl[t][j] = (unsigned char)idx;
            float conf = fminf(1.0f / sden, 1.0f);
            scl[t][j] = (unsigned char)(conf * 255.0f + 0.5f);
        }
        cur ^= 1;
        __syncthreads();
    }

    if (tid == 0) {
        float m = -1e30f; int idx = 0;
        for (int jj = 0; jj < OO; ++jj) {
            float vv = st[cur][jj];
            if (vv > m) { m = vv; idx = jj; }
        }
        float sden = 0.f;
        for (int jj = 0; jj < OO; ++jj)
            sden += __expf(st[cur][jj] - m);

        float* out_tags   = out + (size_t)b * TT;
        float* out_scores = out + (size_t)BB * TT + (size_t)b * TT;
        out_tags[L - 1]   = (float)idx;
        out_scores[L - 1] = 1.0f / sden;

        int tag = idx;
        for (int t = L - 1; t >= 1; --t) {
            int ntag  = bpl[t][tag];
            float sc  = (float)scl[t][tag] * (1.0f / 255.0f);
            out_tags[t - 1]   = (float)ntag;
            out_scores[t - 1] = sc;
            tag = ntag;
        }
    }

    float* out_tags   = out + (size_t)b * TT;
    float* out_scores = out + (size_t)BB * TT + (size_t)b * TT;
    for (int p = L + tid; p < TT; p += 256) {
        out_tags[p]   = 0.f;
        out_scores[p] = 0.f;
    }
}

extern "C" void kernel_launch(void* const* d_in, const int* in_sizes, int n_in,
                              void* d_out, int out_size, void* d_ws, size_t ws_size,
                              hipStream_t stream) {
    const float* logits = (const float*)d_in[0];
    const float* trans  = (const float*)d_in[1];
    const int*   lens   = (const int*)d_in[2];
    float* out = (float*)d_out;

    const size_t m_bytes  = (size_t)BB * TT * OO * sizeof(float); // 64 MB
    const size_t tt_bytes = (size_t)OO * OO * sizeof(float);      // 16 KB
    if (ws_size >= m_bytes + tt_bytes) {
        float* Mst = (float*)d_ws;
        float* Tt  = (float*)((char*)d_ws + m_bytes);
        float* out_tags   = out;
        float* out_scores = out + (size_t)BB * TT;

        crf_transpose<<<1, 256, 0, stream>>>(trans, Tt);
        crf_scan<<<BB, 64, 0, stream>>>(logits, trans, lens, out_tags, Mst);
        crf_conf<<<BB * 128, 256, 0, stream>>>(logits, Mst, Tt, out_tags, lens,
                                               out_scores);
    } else {
        crf_decode_fallback<<<BB, 256, 0, stream>>>(logits, trans, lens, out);
    }
}